// Round 13
// baseline (1978.708 us; speedup 1.0000x reference)
//
#include <hip/hip_runtime.h>
#include <cmath>

// ---------------------------------------------------------------------------
// OmniAnomaly forward — persistent cooperative kernel, fused q+p per CU,
// DECOUPLED q/p wave-level pipelines (round 13).
//
// 256 blocks x 512 threads (8 waves), 1 block/CU. Blocks find their physical
// XCD (HW_REG_XCC_ID) and claim slot 0..31; each XCD owns one 128-row batch
// group. Each CU owns a 16-col slice of BOTH GRUs: waves 0..3 = q-GEMM
// (+ flow on CUs 24..31), waves 4..7 = p-GEMM (+ recon on CUs 0..4).
//
// Round 13 = round-8 base (1662us best; r9-r12 falsified the LDS theory) +
// q/p pipeline decoupling. Since r7 removed A-staging, q-waves and p-waves
// share NO per-phase LDS -> the block-wide barrier was pure over-sync.
// Now: NO __syncthreads in the phase loop. Two independent 32-CU barriers:
//   q-waves: intra-CU aggregate via LDS flags (waves 1-3 flag, wave0 waits,
//            global-arrives one slot/CU, polls 32 q-slots + 32 p-slots in
//            ONE 64-lane load round, LDS-releases; waves 1-3 spin on LDS).
//   p-waves: same with p-slots.
// Cross-pipeline slack checks folded into the poll:
//   p@i needs qslots >= i   (z(i-2) written by flow in q-phase i-1)
//   q@i needs pslots >= i-2 (z parity-4: slot reuse 4 phases deep)
// Each SIMD holds one q-wave + one p-wave -> one pipeline's barrier wait
// hides under the other's compute.
//
// phase i: q-step t=i | flow j=i-1 | p-step u=i-2 | recon v=i-3
// hq/hp parity-2 (intra-pipeline), z parity-4 (cross). h carry in registers.
// A-fragments direct from L2. Proven relaxed-agent atomics + per-wave
// vmcnt(0) before arrival + L1 buffer_inv after release.
// ---------------------------------------------------------------------------

#define B_  1024
#define T_  100
#define XD_ 38
#define H_  500
#define ZD_ 16
#define L_  3
#define NPHASE (T_ + 3)

typedef short bf16x8 __attribute__((ext_vector_type(8)));
typedef float f32x4  __attribute__((ext_vector_type(4)));
typedef unsigned short ushort;

#define HS ((size_t)B_ * 512)   // shorts per h buffer
#define ZS ((size_t)B_ * 32)    // shorts per z buffer

#define MFMA16(a, b, c) __builtin_amdgcn_mfma_f32_16x16x32_bf16((a), (b), (c), 0, 0, 0)

static __device__ __forceinline__ ushort f2bf(float f) {
    union { float f; unsigned u; } v; v.f = f;
    return (ushort)((v.u + 0x7FFF + ((v.u >> 16) & 1)) >> 16);   // RNE
}
static __device__ __forceinline__ float sigf(float x) { return 1.0f / (1.0f + __expf(-x)); }
static __device__ __forceinline__ float tanh_(float x) {
    float e = __expf(2.0f * x);
    return 1.0f - 2.0f / (e + 1.0f);
}
static __device__ __forceinline__ float softplus_(float x) {
    return fmaxf(x, 0.0f) + log1pf(__expf(-fabsf(x)));
}
static __device__ __forceinline__ float grp16_sum(float v) {
    v += __shfl_xor(v, 1, 16);
    v += __shfl_xor(v, 2, 16);
    v += __shfl_xor(v, 4, 16);
    v += __shfl_xor(v, 8, 16);
    return v;
}

// proven sync primitives (rounds 2/4/5/6/7/8 passed with these lowerings)
static __device__ __forceinline__ unsigned aload(const unsigned* p) {
    return __hip_atomic_load(p, __ATOMIC_RELAXED, __HIP_MEMORY_SCOPE_AGENT);
}
static __device__ __forceinline__ void astore(unsigned* p, unsigned v) {
    __hip_atomic_store(p, v, __ATOMIC_RELAXED, __HIP_MEMORY_SCOPE_AGENT);
}

struct OmniArgs {
    const float *x, *eps;
    const float *Wih_q, *Whh_q, *bih_q, *bhh_q;
    const float *Wqm, *bqm, *Wqs, *bqs;
    const float *Wih_p, *Whh_p, *bih_p, *bhh_p;
    const float *Wpm, *bpm, *Wps, *bps;
    const float *fu, *fw, *fb;
    ushort *hqbf, *hpbf, *zbf, *Wqg, *Wpg;
    unsigned *bar;
    float *o_rm, *o_rs, *o_z, *o_zm, *o_zs, *o_ld;
};

// per-pipeline arrive: this WAVE's gating stores drained -> flag.
// waves 1..3: LDS flag. wave0: wait LDS flags (all 4 waves' stores at L2,
// since each did vmcnt(0) before flagging), then global arrive.
static __device__ __forceinline__ void parr(unsigned* mySlots,
                                            volatile unsigned* sfl,
                                            int w2, int lane, int qc,
                                            unsigned tgt) {
    asm volatile("s_waitcnt vmcnt(0)" ::: "memory");
    if (w2 != 0) {
        if (lane == 0) sfl[w2] = tgt;
    } else {
        while (sfl[1] < tgt || sfl[2] < tgt || sfl[3] < tgt)
            __builtin_amdgcn_s_sleep(1);
        if (lane == 0) astore(mySlots + qc * 32, tgt);
    }
}
// per-pipeline wait: wave0 polls own 32 slots (lanes 0..31) AND the other
// pipeline's 32 slots at the slack target (lanes 32..63) in one round, then
// LDS-releases; waves 1..3 spin on the broadcast LDS word.
static __device__ __forceinline__ void pwait(unsigned* mySlots, unsigned* othSlots,
                                             volatile unsigned* sfl,
                                             int w2, int lane,
                                             unsigned tgt, unsigned othNeed) {
    if (w2 == 0) {
        const unsigned* sp = (lane < 32) ? (mySlots + (lane & 31) * 32)
                                         : (othSlots + (lane & 31) * 32);
        const unsigned need = (lane < 32) ? tgt : othNeed;
        for (;;) {
            bool ok = aload(sp) >= need;
            if (__all(ok)) break;
            __builtin_amdgcn_s_sleep(1);
        }
        if (lane == 0) sfl[4] = tgt;
    } else {
        while (sfl[4] < tgt) __builtin_amdgcn_s_sleep(1);
    }
    asm volatile("buffer_inv" ::: "memory");   // L1-only invalidate
}

__global__ __launch_bounds__(512)
void omni_persist(OmniArgs A)
{
    // LDS carve (shorts):
    //  WhlQ [48][520] @0      | WhlP [48][520] @24960
    //  WilQ [48][72]  @49920  | WilP [48][40]  @53376   (total 55296 = 108KB)
    __shared__ ushort lds[55296] __attribute__((aligned(16)));
    __shared__ unsigned sflags[16];   // [0..4] q arr/rel, [8..12] p arr/rel
    __shared__ int sh_gc[2];

    const int tid = threadIdx.x;

    // ---- discover physical XCD, claim slot 0..31 (one-time) ----
    if (tid == 0) {
        unsigned xcd;
        asm volatile("s_getreg_b32 %0, hwreg(HW_REG_XCC_ID)" : "=s"(xcd));
        xcd &= 7u;
        unsigned s = __hip_atomic_fetch_add(A.bar + xcd * 4096 + 2080, 1u,
                                            __ATOMIC_RELAXED, __HIP_MEMORY_SCOPE_AGENT);
        sh_gc[0] = (int)xcd;
        sh_gc[1] = (int)(s & 31u);
    }
    if (tid < 16) sflags[tid] = 0;
    __syncthreads();
    const int grp = sh_gc[0];
    const int qc  = sh_gc[1];              // 0..31
    unsigned* qslots = A.bar + grp * 4096;       // 32 x 32-uint lines
    unsigned* pslots = qslots + 1024;

    const bool isRC = (qc < 5);
    const bool isFL = (qc >= 24);          // flow CUs 24..31
    const int  flowIdx = qc - 24;          // 0..7 (valid when isFL)
    const int  fw2 = flowIdx >> 1;         // which q-wave hosts flow
    const int  fmt = flowIdx & 1;          // which M-tile (16 rows)
    const int  m0 = grp * 128;

    const int gtid = tid & 255;            // index within wave-group
    const bool isQg = (tid < 256);         // waves 0..3 = q, 4..7 = p
    const int w2   = gtid >> 6;            // wave-in-group 0..3
    const int lane = tid & 63;
    const int ln   = lane & 15, qd = lane >> 4;

    const bool fwave = isQg && isFL && (w2 == fw2);   // this wave hosts flow

    ushort* Whl = lds + (isQg ? 0 : 24960);          // [48][520] own GRU
    ushort* Wil = lds + (isQg ? 49920 : 53376);      // q:[48][72] p:[48][40]

    ushort* WqgG = A.Wqg + (size_t)grp * (32 * 544);
    ushort* WpgG = A.Wpg + (size_t)grp * (128 * 512);

    // per-pipeline sync context
    unsigned* mySlots  = isQg ? qslots : pslots;
    unsigned* othSlots = isQg ? pslots : qslots;
    volatile unsigned* sfl = (volatile unsigned*)(isQg ? sflags : sflags + 8);

    // A-fragment row indices (per wave): rows w2*32 + mt*16 + ln
    const int rA0 = m0 + w2*32 + ln;
    const int rA1 = rA0 + 16;
    const int rAf = fmt ? rA1 : rA0;       // flow A row (fwave only)

    // ------------------- prologue: weights -> LDS / global bf16 ------------
    {
        const float* WhhSrc = isQg ? A.Whh_q : A.Whh_p;
        for (int idx = gtid; idx < 3*16*512; idx += 256) {
            int k = idx & 511, n = (idx >> 9) & 15, g = idx >> 13;
            int col = qc*16 + n;
            float v = (k < H_ && col < H_) ? WhhSrc[(size_t)(g*H_ + col)*H_ + k] : 0.f;
            Whl[(g*16 + n)*520 + k] = f2bf(v);
        }
        if (isQg) {
            for (int idx = gtid; idx < 3*16*64; idx += 256) {
                int k = idx & 63, n = (idx >> 6) & 15, g = idx >> 10;
                int col = qc*16 + n;
                float v = (k < XD_ && col < H_) ? A.Wih_q[(size_t)(g*H_+col)*XD_ + k] : 0.f;
                Wil[(g*16 + n)*72 + k] = f2bf(v);
            }
            if (qc == 31) {
                // Wq heads -> per-group bf16 [32][544] (h @0..499, z @512..527)
                for (int idx = gtid; idx < 32*544; idx += 256) {
                    int n = idx / 544, k = idx - n*544;
                    const float* src = (n < 16) ? (A.Wqm + n*(H_+ZD_))
                                                : (A.Wqs + (n-16)*(H_+ZD_));
                    float v = 0.f;
                    if (k < H_) v = src[k];
                    else if (k >= 512 && k < 512 + ZD_) v = src[H_ + (k - 512)];
                    WqgG[idx] = f2bf(v);
                }
            }
        } else {
            for (int idx = gtid; idx < 3*16*32; idx += 256) {
                int k = idx & 31, n = (idx >> 5) & 15, g = idx >> 9;
                int col = qc*16 + n;
                float v = (k < ZD_ && col < H_) ? A.Wih_p[(size_t)(g*H_+col)*ZD_ + k] : 0.f;
                Wil[(g*16 + n)*40 + k] = f2bf(v);
            }
            if (isRC) {
                // recon head rows qc*16..+16 -> per-group bf16 [128][512]
                for (int idx = gtid; idx < 16*512; idx += 256) {
                    int k = idx & 511, n = idx >> 9;
                    int col = qc*16 + n;
                    float v = 0.f;
                    if (k < H_) {
                        if (col < XD_)        v = A.Wpm[(size_t)col*H_ + k];
                        else if (col < 2*XD_) v = A.Wps[(size_t)(col - XD_)*H_ + k];
                    }
                    WpgG[(size_t)(qc*16 + n)*512 + k] = f2bf(v);
                }
            }
        }
    }

    // per-thread constants
    const int colg = qc*16 + ln;           // GRU epilogue h-column
    float bR = 0.f, bZ = 0.f, bNx = 0.f, bNh = 0.f;
    {
        const float* bi = isQg ? A.bih_q : A.bih_p;
        const float* bh = isQg ? A.bhh_q : A.bhh_p;
        if (colg < H_) {
            bR  = bi[colg] + bh[colg];
            bZ  = bi[H_ + colg] + bh[H_ + colg];
            bNx = bi[2*H_ + colg];
            bNh = bh[2*H_ + colg];
        }
    }
    const int colr = qc*16 + ln;           // recon column (p-group, RC CUs)
    float brc = 0.f;
    if (isRC && !isQg) {
        if (colr < XD_) brc = A.bpm[colr];
        else if (colr < 2*XD_) brc = A.bps[colr - XD_];
    }

    // flow constants (lane ln = z-dim)
    float uhv[3], wvv[3], fbv[3], bqm_r = 0.f, bqs_r = 0.f;
    if (isFL) {
        bqm_r = A.bqm[ln]; bqs_r = A.bqs[ln];
        #pragma unroll
        for (int k = 0; k < 3; ++k) {
            float w_ = A.fw[k*ZD_ + ln], u_ = A.fu[k*ZD_ + ln];
            float wu = grp16_sum(w_*u_), ww = grp16_sum(w_*w_);
            uhv[k] = u_ + (-1.f + softplus_(wu) - wu) * w_ / (ww + 1e-6f);
            wvv[k] = w_; fbv[k] = A.fb[k];
        }
    }

    float hold[8];
    #pragma unroll
    for (int r = 0; r < 8; ++r) hold[r] = 0.f;
    float ldacc[4] = {0.f, 0.f, 0.f, 0.f};

    __syncthreads();   // LDS weights + sflags init visible (one-time)

    // ------------------------------ phases ---------------------------------
    for (int i = 0; i < NPHASE; ++i) {
        const int t = i, j = i - 1, u = i - 2, v = i - 3;
        const bool do_q = (t < T_);
        const bool do_f = fwave && (j >= 0) && (j < T_);
        const bool do_p = (u >= 0) && (u < T_);
        const bool do_r = isRC && (v >= 0) && (v < T_);

        const ushort* AgQ = A.hqbf + (size_t)((i-1) & 1) * HS;
        const ushort* AgP = A.hpbf + (size_t)((i-1) & 1) * HS;
        const ushort* ZgP = A.zbf  + (size_t)(u & 3) * ZS;

        f32x4 aR0[2], aR1[2], aNh[2], aNx[2], aC[2], aMf, aSf;
        #pragma unroll
        for (int mt = 0; mt < 2; ++mt) {
            aR0[mt] = f32x4{0.f,0.f,0.f,0.f}; aR1[mt] = f32x4{0.f,0.f,0.f,0.f};
            aNh[mt] = f32x4{0.f,0.f,0.f,0.f}; aNx[mt] = f32x4{0.f,0.f,0.f,0.f};
            aC[mt]  = f32x4{0.f,0.f,0.f,0.f};
        }
        aMf = f32x4{0.f,0.f,0.f,0.f}; aSf = f32x4{0.f,0.f,0.f,0.f};

        if (isQg) {
            // ---------------- q-side: barrier-free k-loop ----------------
            if ((do_q && i > 0) || do_f) {
                #pragma unroll 4
                for (int kt = 0; kt < 16; ++kt) {
                    bf16x8 af0 = *(const bf16x8*)(AgQ + (size_t)rA0*512 + kt*32 + qd*8);
                    bf16x8 af1 = *(const bf16x8*)(AgQ + (size_t)rA1*512 + kt*32 + qd*8);
                    if (do_q) {
                        const ushort* wb = Whl + (size_t)ln*520 + kt*32 + qd*8;
                        bf16x8 b0 = *(const bf16x8*)(wb);
                        bf16x8 b1 = *(const bf16x8*)(wb + 16*520);
                        bf16x8 b2 = *(const bf16x8*)(wb + 32*520);
                        aR0[0] = MFMA16(af0, b0, aR0[0]);  aR0[1] = MFMA16(af1, b0, aR0[1]);
                        aR1[0] = MFMA16(af0, b1, aR1[0]);  aR1[1] = MFMA16(af1, b1, aR1[1]);
                        aNh[0] = MFMA16(af0, b2, aNh[0]);  aNh[1] = MFMA16(af1, b2, aNh[1]);
                    }
                    if (do_f) {
                        bf16x8 bM = *(const bf16x8*)(WqgG + (size_t)ln*544 + kt*32 + qd*8);
                        bf16x8 bS = *(const bf16x8*)(WqgG + (size_t)(16+ln)*544 + kt*32 + qd*8);
                        bf16x8 afx = fmt ? af1 : af0;
                        aMf = MFMA16(afx, bM, aMf);
                        aSf = MFMA16(afx, bS, aSf);
                    }
                }
            }
            if (do_q) {
                // x part (k-tiles 16,17): per-lane f32->bf16 pack
                #pragma unroll
                for (int xt = 0; xt < 2; ++xt) {
                    bf16x8 af[2];
                    #pragma unroll
                    for (int mt = 0; mt < 2; ++mt) {
                        int row = (mt == 0) ? rA0 : rA1;
                        const float* xs = A.x + ((size_t)row*T_ + t)*XD_;
                        int d0 = xt*32 + qd*8;
                        unsigned pk[4];
                        #pragma unroll
                        for (int ii = 0; ii < 4; ++ii) {
                            int d = d0 + ii*2;
                            float v0 = 0.f, v1 = 0.f;
                            if (d + 1 < XD_) { float2 f = *(const float2*)(xs + d); v0 = f.x; v1 = f.y; }
                            else if (d < XD_) v0 = xs[d];
                            pk[ii] = (unsigned)f2bf(v0) | ((unsigned)f2bf(v1) << 16);
                        }
                        uint4 pa = make_uint4(pk[0], pk[1], pk[2], pk[3]);
                        af[mt] = *(bf16x8*)&pa;
                    }
                    const ushort* wb = Wil + (size_t)ln*72 + xt*32 + qd*8;
                    bf16x8 b0 = *(const bf16x8*)(wb);
                    bf16x8 b1 = *(const bf16x8*)(wb + 16*72);
                    bf16x8 b2 = *(const bf16x8*)(wb + 32*72);
                    aR0[0] = MFMA16(af[0], b0, aR0[0]);  aR0[1] = MFMA16(af[1], b0, aR0[1]);
                    aR1[0] = MFMA16(af[0], b1, aR1[0]);  aR1[1] = MFMA16(af[1], b1, aR1[1]);
                    aNx[0] = MFMA16(af[0], b2, aNx[0]);  aNx[1] = MFMA16(af[1], b2, aNx[1]);
                }
            }
        } else {
            // ---------------- p-side: barrier-free k-loop ----------------
            if ((do_p && u > 0) || do_r) {
                #pragma unroll 4
                for (int kt = 0; kt < 16; ++kt) {
                    bf16x8 af0 = *(const bf16x8*)(AgP + (size_t)rA0*512 + kt*32 + qd*8);
                    bf16x8 af1 = *(const bf16x8*)(AgP + (size_t)rA1*512 + kt*32 + qd*8);
                    if (do_p) {
                        const ushort* wb = Whl + (size_t)ln*520 + kt*32 + qd*8;
                        bf16x8 b0 = *(const bf16x8*)(wb);
                        bf16x8 b1 = *(const bf16x8*)(wb + 16*520);
                        bf16x8 b2 = *(const bf16x8*)(wb + 32*520);
                        aR0[0] = MFMA16(af0, b0, aR0[0]);  aR0[1] = MFMA16(af1, b0, aR0[1]);
                        aR1[0] = MFMA16(af0, b1, aR1[0]);  aR1[1] = MFMA16(af1, b1, aR1[1]);
                        aNh[0] = MFMA16(af0, b2, aNh[0]);  aNh[1] = MFMA16(af1, b2, aNh[1]);
                    }
                    if (do_r) {
                        bf16x8 bC = *(const bf16x8*)(WpgG + (size_t)(qc*16+ln)*512 + kt*32 + qd*8);
                        aC[0] = MFMA16(af0, bC, aC[0]);  aC[1] = MFMA16(af1, bC, aC[1]);
                    }
                }
            }
            if (do_p) {
                // z part (k-tile 16): direct from z buffer (upper 16 zeroed)
                bf16x8 af0 = *(const bf16x8*)(ZgP + (size_t)rA0*32 + qd*8);
                bf16x8 af1 = *(const bf16x8*)(ZgP + (size_t)rA1*32 + qd*8);
                const ushort* wb = Wil + (size_t)ln*40 + qd*8;
                bf16x8 b0 = *(const bf16x8*)(wb);
                bf16x8 b1 = *(const bf16x8*)(wb + 16*40);
                bf16x8 b2 = *(const bf16x8*)(wb + 32*40);
                aR0[0] = MFMA16(af0, b0, aR0[0]);  aR0[1] = MFMA16(af1, b0, aR0[1]);
                aR1[0] = MFMA16(af0, b1, aR1[0]);  aR1[1] = MFMA16(af1, b1, aR1[1]);
                aNx[0] = MFMA16(af0, b2, aNx[0]);  aNx[1] = MFMA16(af1, b2, aNx[1]);
            }
        }

        // ---- GRU epilogues (carry in registers) -> h stores gate arrival ----
        if (isQg && do_q) {
            ushort* Hb = A.hqbf + (size_t)(i & 1) * HS;
            #pragma unroll
            for (int mt = 0; mt < 2; ++mt)
                #pragma unroll
                for (int r = 0; r < 4; ++r) {
                    int row = m0 + w2*32 + mt*16 + qd*4 + r;
                    float rg = sigf(aR0[mt][r] + bR);
                    float zg = sigf(aR1[mt][r] + bZ);
                    float ng = tanh_(aNx[mt][r] + bNx + rg*(aNh[mt][r] + bNh));
                    float hn = (1.f - zg)*ng + zg*hold[mt*4 + r];
                    if (colg >= H_) hn = 0.f;
                    hold[mt*4 + r] = hn;
                    Hb[(size_t)row*512 + colg] = f2bf(hn);
                }
        }
        if (!isQg && do_p) {
            ushort* Hb = A.hpbf + (size_t)(i & 1) * HS;
            #pragma unroll
            for (int mt = 0; mt < 2; ++mt)
                #pragma unroll
                for (int r = 0; r < 4; ++r) {
                    int row = m0 + w2*32 + mt*16 + qd*4 + r;
                    float rg = sigf(aR0[mt][r] + bR);
                    float zg = sigf(aR1[mt][r] + bZ);
                    float ng = tanh_(aNx[mt][r] + bNx + rg*(aNh[mt][r] + bNh));
                    float hn = (1.f - zg)*ng + zg*hold[mt*4 + r];
                    if (colg >= H_) hn = 0.f;
                    hold[mt*4 + r] = hn;
                    Hb[(size_t)row*512 + colg] = f2bf(hn);
                }
        }

        // ---- flow finish (in-register, 4 rows/thread) -> z store gates arr.
        float mu4[4], sd4[4], zk4[4];
        if (do_f) {
            if (j >= 1) {   // z-concat MFMA (A and B direct from L2; own rows)
                const ushort* zp = A.zbf + (size_t)((j-1) & 3) * ZS;
                bf16x8 bMz = *(const bf16x8*)(WqgG + (size_t)ln*544 + 512 + qd*8);
                bf16x8 bSz = *(const bf16x8*)(WqgG + (size_t)(16+ln)*544 + 512 + qd*8);
                bf16x8 az  = *(const bf16x8*)(zp + (size_t)rAf*32 + qd*8);
                aMf = MFMA16(az, bMz, aMf);
                aSf = MFMA16(az, bSz, aSf);
            }
            ushort* Zo = A.zbf + (size_t)(j & 3) * ZS;
            #pragma unroll
            for (int r = 0; r < 4; ++r) {
                int row = m0 + flowIdx*16 + qd*4 + r;
                float mu = aMf[r] + bqm_r;
                float sd = softplus_(aSf[r] + bqs_r) + 1e-4f;
                float ep = A.eps[((size_t)row*T_ + j)*ZD_ + ln];
                float zk = mu + ep*sd;
                mu4[r] = mu; sd4[r] = sd;
                float lsum = 0.f;
                #pragma unroll
                for (int k = 0; k < 3; ++k) {
                    float th = tanh_(grp16_sum(zk*wvv[k]) + fbv[k]);
                    zk = fmaf(uhv[k], th, zk);
                    float det = 1.f + grp16_sum((1.f - th*th)*wvv[k]*uhv[k]);
                    lsum += logf(fabsf(det) + 1e-6f);
                }
                zk4[r] = zk; ldacc[r] += lsum;
                Zo[(size_t)row*32 + ln] = f2bf(zk);
                if (j < 4) Zo[(size_t)row*32 + 16 + ln] = 0;   // all 4 parities
            }
        }

        // ---- per-pipeline arrival (own stores drained), outputs overlap ----
        const unsigned tgt = (unsigned)(i + 1);
        // q@(i+1) overwrites z slot i&3 = z(i-4), read by p@(i-2):
        //   need pslots >= i-1 = tgt-2. p@(i+1) needs q done phase i: qslots>=tgt.
        const unsigned othNeed = isQg ? (tgt >= 3 ? tgt - 2 : 0) : tgt;

        parr(mySlots, sfl, w2, lane, qc, tgt);

        if (do_f) {
            #pragma unroll
            for (int r = 0; r < 4; ++r) {
                int row = m0 + flowIdx*16 + qd*4 + r;
                size_t oi = ((size_t)row*T_ + j)*ZD_ + ln;
                A.o_zm[oi] = mu4[r];
                A.o_zs[oi] = sd4[r];
                A.o_z[oi]  = zk4[r];
                if (j == T_ - 1 && ln == 0) A.o_ld[row] = ldacc[r];
            }
        }
        if (!isQg && do_r) {
            #pragma unroll
            for (int mt = 0; mt < 2; ++mt)
                #pragma unroll
                for (int r = 0; r < 4; ++r) {
                    int row = m0 + w2*32 + mt*16 + qd*4 + r;
                    size_t ob = ((size_t)row*T_ + v)*XD_;
                    float a = aC[mt][r];
                    if (colr < XD_)        A.o_rm[ob + colr] = a + brc;
                    else if (colr < 2*XD_) A.o_rs[ob + (colr - XD_)] =
                                               softplus_(a + brc) + 1e-4f;
                }
        }

        if (i < NPHASE - 1)
            pwait(mySlots, othSlots, sfl, w2, lane, tgt, othNeed);
    }
}

// ---------------------------------------------------------------------------
extern "C" void kernel_launch(void* const* d_in, const int* in_sizes, int n_in,
                              void* d_out, int out_size, void* d_ws, size_t ws_size,
                              hipStream_t stream)
{
    (void)in_sizes; (void)n_in; (void)out_size; (void)ws_size;
    float* out = (float*)d_out;

    char* p = (char*)d_ws;
    auto alloc = [&](size_t bytes) { void* r = p; p += (bytes + 255) & ~(size_t)255; return r; };
    const size_t HSb = (size_t)1024 * 512 * sizeof(ushort);
    ushort* hqbf = (ushort*)alloc(2 * HSb);
    ushort* hpbf = (ushort*)alloc(2 * HSb);
    ushort* zbf  = (ushort*)alloc(4 * (size_t)1024 * 32 * sizeof(ushort));
    ushort* Wqg  = (ushort*)alloc((size_t)8 * 32 * 544 * sizeof(ushort));
    ushort* Wpg  = (ushort*)alloc((size_t)8 * 128 * 512 * sizeof(ushort));
    unsigned* bar = (unsigned*)alloc((size_t)8 * 4096 * sizeof(unsigned));

    hipMemsetAsync(bar, 0, (size_t)8 * 4096 * sizeof(unsigned), stream);

    OmniArgs a;
    a.x     = (const float*)d_in[0];
    a.eps   = (const float*)d_in[1];
    a.Wih_q = (const float*)d_in[2];
    a.Whh_q = (const float*)d_in[3];
    a.bih_q = (const float*)d_in[4];
    a.bhh_q = (const float*)d_in[5];
    a.Wqm   = (const float*)d_in[6];
    a.bqm   = (const float*)d_in[7];
    a.Wqs   = (const float*)d_in[8];
    a.bqs   = (const float*)d_in[9];
    a.Wih_p = (const float*)d_in[10];
    a.Whh_p = (const float*)d_in[11];
    a.bih_p = (const float*)d_in[12];
    a.bhh_p = (const float*)d_in[13];
    a.Wpm   = (const float*)d_in[14];
    a.bpm   = (const float*)d_in[15];
    a.Wps   = (const float*)d_in[16];
    a.bps   = (const float*)d_in[17];
    a.fu    = (const float*)d_in[18];
    a.fw    = (const float*)d_in[19];
    a.fb    = (const float*)d_in[20];
    a.hqbf = hqbf; a.hpbf = hpbf; a.zbf = zbf; a.Wqg = Wqg; a.Wpg = Wpg; a.bar = bar;
    a.o_rm = out;
    a.o_rs = out + 3891200;
    a.o_z  = out + 7782400;
    a.o_zm = out + 9420800;
    a.o_zs = out + 11059200;
    a.o_ld = out + 12697600;

    void* kargs[] = { &a };
    hipError_t err = hipLaunchCooperativeKernel((void*)omni_persist, dim3(256), dim3(512),
                                                kargs, 0, stream);
    if (err != hipSuccess) {
        // fallback: plain launch — 256 blocks, 1 block/CU, all co-resident.
        (void)hipGetLastError();
        hipLaunchKernelGGL(omni_persist, dim3(256), dim3(512), 0, stream, a);
    }
}

// Round 14
// 1649.943 us; speedup vs baseline: 1.1993x; 1.1993x over previous
//
#include <hip/hip_runtime.h>
#include <cmath>

// ---------------------------------------------------------------------------
// OmniAnomaly forward — persistent cooperative kernel, fused q+p per CU.
// ROUND 14 = byte-level revert to the round-8 optimum (1662 us verified).
//
// 256 blocks x 512 threads (8 waves), 1 block/CU. Blocks find their physical
// XCD (HW_REG_XCC_ID) and claim slot 0..31; each XCD owns one 128-row batch
// group. Each CU owns a 16-col slice of BOTH GRUs: waves 0..3 = q-GEMM,
// waves 4..7 = p-GEMM (+ recon on CUs 0..4). Flow on CUs 24..31 (one wave,
// one 16-row M-tile each, in-register epilogue).
//
// Key structure (each element verified by within-session A/B):
//  * barrier-free k-loops: A-fragments direct from L2 (staging removal was
//    +25%, r7); B weights resident in LDS (VGPR-cache and global-pack
//    alternatives both falsified, r9-r12).
//  * flow spread over 8 CUs, 4-rows/thread in-register epilogue (r8, +9%).
//  * one-hop barrier: plain-store arrival to a private line; every CU's
//    wave0 polls all 32 slots; pure outputs stored AFTER arrival so they
//    overlap the wait (r8). Block-wide sync beats decoupled q/p (r13).
//
// phase i: q-step t=i | flow j=i-1 | p-step u=i-2 | recon v=i-3
// hq/hp/z parity-2. GRU carry h in registers.
// Sync: relaxed-agent atomics + vmcnt(0) before arrival + L1 buffer_inv.
// ---------------------------------------------------------------------------

#define B_  1024
#define T_  100
#define XD_ 38
#define H_  500
#define ZD_ 16
#define L_  3
#define NPHASE (T_ + 3)

typedef short bf16x8 __attribute__((ext_vector_type(8)));
typedef float f32x4  __attribute__((ext_vector_type(4)));
typedef unsigned short ushort;

#define HS ((size_t)B_ * 512)   // shorts per h buffer
#define ZS ((size_t)B_ * 32)    // shorts per z buffer

#define MFMA16(a, b, c) __builtin_amdgcn_mfma_f32_16x16x32_bf16((a), (b), (c), 0, 0, 0)

static __device__ __forceinline__ ushort f2bf(float f) {
    union { float f; unsigned u; } v; v.f = f;
    return (ushort)((v.u + 0x7FFF + ((v.u >> 16) & 1)) >> 16);   // RNE
}
static __device__ __forceinline__ float sigf(float x) { return 1.0f / (1.0f + __expf(-x)); }
static __device__ __forceinline__ float tanh_(float x) {
    float e = __expf(2.0f * x);
    return 1.0f - 2.0f / (e + 1.0f);
}
static __device__ __forceinline__ float softplus_(float x) {
    return fmaxf(x, 0.0f) + log1pf(__expf(-fabsf(x)));
}
static __device__ __forceinline__ float grp16_sum(float v) {
    v += __shfl_xor(v, 1, 16);
    v += __shfl_xor(v, 2, 16);
    v += __shfl_xor(v, 4, 16);
    v += __shfl_xor(v, 8, 16);
    return v;
}

// proven sync primitives (rounds 2/4/5/6/7/8 passed with these lowerings)
static __device__ __forceinline__ unsigned aload(const unsigned* p) {
    return __hip_atomic_load(p, __ATOMIC_RELAXED, __HIP_MEMORY_SCOPE_AGENT);
}
static __device__ __forceinline__ void astore(unsigned* p, unsigned v) {
    __hip_atomic_store(p, v, __ATOMIC_RELAXED, __HIP_MEMORY_SCOPE_AGENT);
}

struct OmniArgs {
    const float *x, *eps;
    const float *Wih_q, *Whh_q, *bih_q, *bhh_q;
    const float *Wqm, *bqm, *Wqs, *bqs;
    const float *Wih_p, *Whh_p, *bih_p, *bhh_p;
    const float *Wpm, *bpm, *Wps, *bps;
    const float *fu, *fw, *fb;
    ushort *hqbf, *hpbf, *zbf, *Wqg, *Wpg;
    unsigned *bar;
    float *o_rm, *o_rs, *o_z, *o_zm, *o_zs, *o_ld;
};

// arrival: drain this wave's gating stores (h, z) to L2, block-sync, store slot.
static __device__ __forceinline__ void arrive(unsigned* slots, int slot,
                                              unsigned tgt, int tid) {
    asm volatile("s_waitcnt vmcnt(0)" ::: "memory");
    __syncthreads();
    if (tid == 0) astore(slots + slot * 32, tgt);
}
// wait: wave0 polls all 32 slots (lanes 32-63 duplicate so __all works).
static __device__ __forceinline__ void waitall(unsigned* slots, unsigned tgt,
                                               int tid) {
    if (tid < 64) {
        const unsigned* sp = slots + (tid & 31) * 32;
        for (;;) {
            bool ok = aload(sp) >= tgt;
            if (__all(ok)) break;
            __builtin_amdgcn_s_sleep(1);
        }
    }
    __syncthreads();
    asm volatile("buffer_inv" ::: "memory");   // L1-only invalidate
}

__global__ __launch_bounds__(512)
void omni_persist(OmniArgs A)
{
    // LDS carve (shorts):
    //  WhlQ [48][520] @0      | WhlP [48][520] @24960
    //  WilQ [48][72]  @49920  | WilP [48][40]  @53376   (total 55296 = 108KB)
    __shared__ ushort lds[55296] __attribute__((aligned(16)));
    __shared__ int sh_gc[2];

    const int tid = threadIdx.x;

    // ---- discover physical XCD, claim slot 0..31 (one-time) ----
    if (tid == 0) {
        unsigned xcd;
        asm volatile("s_getreg_b32 %0, hwreg(HW_REG_XCC_ID)" : "=s"(xcd));
        xcd &= 7u;
        unsigned s = __hip_atomic_fetch_add(A.bar + xcd * 2048 + 1152, 1u,
                                            __ATOMIC_RELAXED, __HIP_MEMORY_SCOPE_AGENT);
        sh_gc[0] = (int)xcd;
        sh_gc[1] = (int)(s & 31u);
    }
    __syncthreads();
    const int grp = sh_gc[0];
    const int qc  = sh_gc[1];              // 0..31
    unsigned* slots = A.bar + grp * 2048;

    const bool isRC = (qc < 5);
    const bool isFL = (qc >= 24);          // flow CUs 24..31
    const int  flowIdx = qc - 24;          // 0..7 (valid when isFL)
    const int  fw2 = flowIdx >> 1;         // which q-wave hosts flow
    const int  fmt = flowIdx & 1;          // which M-tile (16 rows)
    const int  m0 = grp * 128;

    const int gtid = tid & 255;            // index within wave-group
    const bool isQg = (tid < 256);         // waves 0..3 = q, 4..7 = p
    const int w2   = gtid >> 6;            // wave-in-group 0..3
    const int lane = tid & 63;
    const int ln   = lane & 15, qd = lane >> 4;

    const bool fwave = isQg && isFL && (w2 == fw2);   // this wave hosts flow

    ushort* Whl = lds + (isQg ? 0 : 24960);          // [48][520] own GRU
    ushort* Wil = lds + (isQg ? 49920 : 53376);      // q:[48][72] p:[48][40]

    ushort* WqgG = A.Wqg + (size_t)grp * (32 * 544);
    ushort* WpgG = A.Wpg + (size_t)grp * (128 * 512);

    // A-fragment row indices (per wave): rows w2*32 + mt*16 + ln
    const int rA0 = m0 + w2*32 + ln;
    const int rA1 = rA0 + 16;
    const int rAf = fmt ? rA1 : rA0;       // flow A row (fwave only)

    // ------------------- prologue: weights -> LDS / global bf16 ------------
    {
        const float* WhhSrc = isQg ? A.Whh_q : A.Whh_p;
        for (int idx = gtid; idx < 3*16*512; idx += 256) {
            int k = idx & 511, n = (idx >> 9) & 15, g = idx >> 13;
            int col = qc*16 + n;
            float v = (k < H_ && col < H_) ? WhhSrc[(size_t)(g*H_ + col)*H_ + k] : 0.f;
            Whl[(g*16 + n)*520 + k] = f2bf(v);
        }
        if (isQg) {
            for (int idx = gtid; idx < 3*16*64; idx += 256) {
                int k = idx & 63, n = (idx >> 6) & 15, g = idx >> 10;
                int col = qc*16 + n;
                float v = (k < XD_ && col < H_) ? A.Wih_q[(size_t)(g*H_+col)*XD_ + k] : 0.f;
                Wil[(g*16 + n)*72 + k] = f2bf(v);
            }
            if (qc == 31) {
                // Wq heads -> per-group bf16 [32][544] (h @0..499, z @512..527)
                for (int idx = gtid; idx < 32*544; idx += 256) {
                    int n = idx / 544, k = idx - n*544;
                    const float* src = (n < 16) ? (A.Wqm + n*(H_+ZD_))
                                                : (A.Wqs + (n-16)*(H_+ZD_));
                    float v = 0.f;
                    if (k < H_) v = src[k];
                    else if (k >= 512 && k < 512 + ZD_) v = src[H_ + (k - 512)];
                    WqgG[idx] = f2bf(v);
                }
            }
        } else {
            for (int idx = gtid; idx < 3*16*32; idx += 256) {
                int k = idx & 31, n = (idx >> 5) & 15, g = idx >> 9;
                int col = qc*16 + n;
                float v = (k < ZD_ && col < H_) ? A.Wih_p[(size_t)(g*H_+col)*ZD_ + k] : 0.f;
                Wil[(g*16 + n)*40 + k] = f2bf(v);
            }
            if (isRC) {
                // recon head rows qc*16..+16 -> per-group bf16 [128][512]
                for (int idx = gtid; idx < 16*512; idx += 256) {
                    int k = idx & 511, n = idx >> 9;
                    int col = qc*16 + n;
                    float v = 0.f;
                    if (k < H_) {
                        if (col < XD_)        v = A.Wpm[(size_t)col*H_ + k];
                        else if (col < 2*XD_) v = A.Wps[(size_t)(col - XD_)*H_ + k];
                    }
                    WpgG[(size_t)(qc*16 + n)*512 + k] = f2bf(v);
                }
            }
        }
    }

    // per-thread constants
    const int colg = qc*16 + ln;           // GRU epilogue h-column
    float bR = 0.f, bZ = 0.f, bNx = 0.f, bNh = 0.f;
    {
        const float* bi = isQg ? A.bih_q : A.bih_p;
        const float* bh = isQg ? A.bhh_q : A.bhh_p;
        if (colg < H_) {
            bR  = bi[colg] + bh[colg];
            bZ  = bi[H_ + colg] + bh[H_ + colg];
            bNx = bi[2*H_ + colg];
            bNh = bh[2*H_ + colg];
        }
    }
    const int colr = qc*16 + ln;           // recon column (p-group, RC CUs)
    float brc = 0.f;
    if (isRC && !isQg) {
        if (colr < XD_) brc = A.bpm[colr];
        else if (colr < 2*XD_) brc = A.bps[colr - XD_];
    }

    // flow constants (lane ln = z-dim)
    float uhv[3], wvv[3], fbv[3], bqm_r = 0.f, bqs_r = 0.f;
    if (isFL) {
        bqm_r = A.bqm[ln]; bqs_r = A.bqs[ln];
        #pragma unroll
        for (int k = 0; k < 3; ++k) {
            float w_ = A.fw[k*ZD_ + ln], u_ = A.fu[k*ZD_ + ln];
            float wu = grp16_sum(w_*u_), ww = grp16_sum(w_*w_);
            uhv[k] = u_ + (-1.f + softplus_(wu) - wu) * w_ / (ww + 1e-6f);
            wvv[k] = w_; fbv[k] = A.fb[k];
        }
    }

    float hold[8];
    #pragma unroll
    for (int r = 0; r < 8; ++r) hold[r] = 0.f;
    float ldacc[4] = {0.f, 0.f, 0.f, 0.f};

    __syncthreads();   // LDS weights visible to all waves

    // ------------------------------ phases ---------------------------------
    for (int i = 0; i < NPHASE; ++i) {
        const int t = i, j = i - 1, u = i - 2, v = i - 3;
        const bool do_q = (t < T_);
        const bool do_f = fwave && (j >= 0) && (j < T_);
        const bool do_p = (u >= 0) && (u < T_);
        const bool do_r = isRC && (v >= 0) && (v < T_);

        const ushort* AgQ = A.hqbf + (size_t)((i-1) & 1) * HS;
        const ushort* AgP = A.hpbf + (size_t)((i-1) & 1) * HS;
        const ushort* ZgP = A.zbf  + (size_t)(u & 1) * ZS;

        f32x4 aR0[2], aR1[2], aNh[2], aNx[2], aC[2], aMf, aSf;
        #pragma unroll
        for (int mt = 0; mt < 2; ++mt) {
            aR0[mt] = f32x4{0.f,0.f,0.f,0.f}; aR1[mt] = f32x4{0.f,0.f,0.f,0.f};
            aNh[mt] = f32x4{0.f,0.f,0.f,0.f}; aNx[mt] = f32x4{0.f,0.f,0.f,0.f};
            aC[mt]  = f32x4{0.f,0.f,0.f,0.f};
        }
        aMf = f32x4{0.f,0.f,0.f,0.f}; aSf = f32x4{0.f,0.f,0.f,0.f};

        if (isQg) {
            // ---------------- q-side: barrier-free k-loop ----------------
            if ((do_q && i > 0) || do_f) {
                #pragma unroll 4
                for (int kt = 0; kt < 16; ++kt) {
                    bf16x8 af0 = *(const bf16x8*)(AgQ + (size_t)rA0*512 + kt*32 + qd*8);
                    bf16x8 af1 = *(const bf16x8*)(AgQ + (size_t)rA1*512 + kt*32 + qd*8);
                    if (do_q) {
                        const ushort* wb = Whl + (size_t)ln*520 + kt*32 + qd*8;
                        bf16x8 b0 = *(const bf16x8*)(wb);
                        bf16x8 b1 = *(const bf16x8*)(wb + 16*520);
                        bf16x8 b2 = *(const bf16x8*)(wb + 32*520);
                        aR0[0] = MFMA16(af0, b0, aR0[0]);  aR0[1] = MFMA16(af1, b0, aR0[1]);
                        aR1[0] = MFMA16(af0, b1, aR1[0]);  aR1[1] = MFMA16(af1, b1, aR1[1]);
                        aNh[0] = MFMA16(af0, b2, aNh[0]);  aNh[1] = MFMA16(af1, b2, aNh[1]);
                    }
                    if (do_f) {
                        bf16x8 bM = *(const bf16x8*)(WqgG + (size_t)ln*544 + kt*32 + qd*8);
                        bf16x8 bS = *(const bf16x8*)(WqgG + (size_t)(16+ln)*544 + kt*32 + qd*8);
                        bf16x8 afx = fmt ? af1 : af0;
                        aMf = MFMA16(afx, bM, aMf);
                        aSf = MFMA16(afx, bS, aSf);
                    }
                }
            }
            if (do_q) {
                // x part (k-tiles 16,17): per-lane f32->bf16 pack
                #pragma unroll
                for (int xt = 0; xt < 2; ++xt) {
                    bf16x8 af[2];
                    #pragma unroll
                    for (int mt = 0; mt < 2; ++mt) {
                        int row = (mt == 0) ? rA0 : rA1;
                        const float* xs = A.x + ((size_t)row*T_ + t)*XD_;
                        int d0 = xt*32 + qd*8;
                        unsigned pk[4];
                        #pragma unroll
                        for (int ii = 0; ii < 4; ++ii) {
                            int d = d0 + ii*2;
                            float v0 = 0.f, v1 = 0.f;
                            if (d + 1 < XD_) { float2 f = *(const float2*)(xs + d); v0 = f.x; v1 = f.y; }
                            else if (d < XD_) v0 = xs[d];
                            pk[ii] = (unsigned)f2bf(v0) | ((unsigned)f2bf(v1) << 16);
                        }
                        uint4 pa = make_uint4(pk[0], pk[1], pk[2], pk[3]);
                        af[mt] = *(bf16x8*)&pa;
                    }
                    const ushort* wb = Wil + (size_t)ln*72 + xt*32 + qd*8;
                    bf16x8 b0 = *(const bf16x8*)(wb);
                    bf16x8 b1 = *(const bf16x8*)(wb + 16*72);
                    bf16x8 b2 = *(const bf16x8*)(wb + 32*72);
                    aR0[0] = MFMA16(af[0], b0, aR0[0]);  aR0[1] = MFMA16(af[1], b0, aR0[1]);
                    aR1[0] = MFMA16(af[0], b1, aR1[0]);  aR1[1] = MFMA16(af[1], b1, aR1[1]);
                    aNx[0] = MFMA16(af[0], b2, aNx[0]);  aNx[1] = MFMA16(af[1], b2, aNx[1]);
                }
            }
        } else {
            // ---------------- p-side: barrier-free k-loop ----------------
            if ((do_p && u > 0) || do_r) {
                #pragma unroll 4
                for (int kt = 0; kt < 16; ++kt) {
                    bf16x8 af0 = *(const bf16x8*)(AgP + (size_t)rA0*512 + kt*32 + qd*8);
                    bf16x8 af1 = *(const bf16x8*)(AgP + (size_t)rA1*512 + kt*32 + qd*8);
                    if (do_p) {
                        const ushort* wb = Whl + (size_t)ln*520 + kt*32 + qd*8;
                        bf16x8 b0 = *(const bf16x8*)(wb);
                        bf16x8 b1 = *(const bf16x8*)(wb + 16*520);
                        bf16x8 b2 = *(const bf16x8*)(wb + 32*520);
                        aR0[0] = MFMA16(af0, b0, aR0[0]);  aR0[1] = MFMA16(af1, b0, aR0[1]);
                        aR1[0] = MFMA16(af0, b1, aR1[0]);  aR1[1] = MFMA16(af1, b1, aR1[1]);
                        aNh[0] = MFMA16(af0, b2, aNh[0]);  aNh[1] = MFMA16(af1, b2, aNh[1]);
                    }
                    if (do_r) {
                        bf16x8 bC = *(const bf16x8*)(WpgG + (size_t)(qc*16+ln)*512 + kt*32 + qd*8);
                        aC[0] = MFMA16(af0, bC, aC[0]);  aC[1] = MFMA16(af1, bC, aC[1]);
                    }
                }
            }
            if (do_p) {
                // z part (k-tile 16): direct from z buffer (upper 16 zeroed)
                bf16x8 af0 = *(const bf16x8*)(ZgP + (size_t)rA0*32 + qd*8);
                bf16x8 af1 = *(const bf16x8*)(ZgP + (size_t)rA1*32 + qd*8);
                const ushort* wb = Wil + (size_t)ln*40 + qd*8;
                bf16x8 b0 = *(const bf16x8*)(wb);
                bf16x8 b1 = *(const bf16x8*)(wb + 16*40);
                bf16x8 b2 = *(const bf16x8*)(wb + 32*40);
                aR0[0] = MFMA16(af0, b0, aR0[0]);  aR0[1] = MFMA16(af1, b0, aR0[1]);
                aR1[0] = MFMA16(af0, b1, aR1[0]);  aR1[1] = MFMA16(af1, b1, aR1[1]);
                aNx[0] = MFMA16(af0, b2, aNx[0]);  aNx[1] = MFMA16(af1, b2, aNx[1]);
            }
        }

        // ---- GRU epilogues (carry in registers) -> h stores gate arrival ----
        if (isQg && do_q) {
            ushort* Hb = A.hqbf + (size_t)(i & 1) * HS;
            #pragma unroll
            for (int mt = 0; mt < 2; ++mt)
                #pragma unroll
                for (int r = 0; r < 4; ++r) {
                    int row = m0 + w2*32 + mt*16 + qd*4 + r;
                    float rg = sigf(aR0[mt][r] + bR);
                    float zg = sigf(aR1[mt][r] + bZ);
                    float ng = tanh_(aNx[mt][r] + bNx + rg*(aNh[mt][r] + bNh));
                    float hn = (1.f - zg)*ng + zg*hold[mt*4 + r];
                    if (colg >= H_) hn = 0.f;
                    hold[mt*4 + r] = hn;
                    Hb[(size_t)row*512 + colg] = f2bf(hn);
                }
        }
        if (!isQg && do_p) {
            ushort* Hb = A.hpbf + (size_t)(i & 1) * HS;
            #pragma unroll
            for (int mt = 0; mt < 2; ++mt)
                #pragma unroll
                for (int r = 0; r < 4; ++r) {
                    int row = m0 + w2*32 + mt*16 + qd*4 + r;
                    float rg = sigf(aR0[mt][r] + bR);
                    float zg = sigf(aR1[mt][r] + bZ);
                    float ng = tanh_(aNx[mt][r] + bNx + rg*(aNh[mt][r] + bNh));
                    float hn = (1.f - zg)*ng + zg*hold[mt*4 + r];
                    if (colg >= H_) hn = 0.f;
                    hold[mt*4 + r] = hn;
                    Hb[(size_t)row*512 + colg] = f2bf(hn);
                }
        }

        // ---- flow finish (in-register, 4 rows/thread) -> z store gates arr.
        float mu4[4], sd4[4], zk4[4];
        if (do_f) {
            if (j >= 1) {   // z-concat MFMA (A and B direct from L2)
                const ushort* zp = A.zbf + (size_t)((j-1) & 1) * ZS;
                bf16x8 bMz = *(const bf16x8*)(WqgG + (size_t)ln*544 + 512 + qd*8);
                bf16x8 bSz = *(const bf16x8*)(WqgG + (size_t)(16+ln)*544 + 512 + qd*8);
                bf16x8 az  = *(const bf16x8*)(zp + (size_t)rAf*32 + qd*8);
                aMf = MFMA16(az, bMz, aMf);
                aSf = MFMA16(az, bSz, aSf);
            }
            ushort* Zo = A.zbf + (size_t)(j & 1) * ZS;
            #pragma unroll
            for (int r = 0; r < 4; ++r) {
                int row = m0 + flowIdx*16 + qd*4 + r;
                float mu = aMf[r] + bqm_r;
                float sd = softplus_(aSf[r] + bqs_r) + 1e-4f;
                float ep = A.eps[((size_t)row*T_ + j)*ZD_ + ln];
                float zk = mu + ep*sd;
                mu4[r] = mu; sd4[r] = sd;
                float lsum = 0.f;
                #pragma unroll
                for (int k = 0; k < 3; ++k) {
                    float th = tanh_(grp16_sum(zk*wvv[k]) + fbv[k]);
                    zk = fmaf(uhv[k], th, zk);
                    float det = 1.f + grp16_sum((1.f - th*th)*wvv[k]*uhv[k]);
                    lsum += logf(fabsf(det) + 1e-6f);
                }
                zk4[r] = zk; ldacc[r] += lsum;
                Zo[(size_t)row*32 + ln]      = f2bf(zk);
                Zo[(size_t)row*32 + 16 + ln] = 0;
            }
        }

        // ---- arrival (h+z drained), then pure outputs overlap the wait ----
        arrive(slots, qc, (unsigned)(i + 1), tid);

        if (do_f) {
            #pragma unroll
            for (int r = 0; r < 4; ++r) {
                int row = m0 + flowIdx*16 + qd*4 + r;
                size_t oi = ((size_t)row*T_ + j)*ZD_ + ln;
                A.o_zm[oi] = mu4[r];
                A.o_zs[oi] = sd4[r];
                A.o_z[oi]  = zk4[r];
                if (j == T_ - 1 && ln == 0) A.o_ld[row] = ldacc[r];
            }
        }
        if (!isQg && do_r) {
            #pragma unroll
            for (int mt = 0; mt < 2; ++mt)
                #pragma unroll
                for (int r = 0; r < 4; ++r) {
                    int row = m0 + w2*32 + mt*16 + qd*4 + r;
                    size_t ob = ((size_t)row*T_ + v)*XD_;
                    float a = aC[mt][r];
                    if (colr < XD_)        A.o_rm[ob + colr] = a + brc;
                    else if (colr < 2*XD_) A.o_rs[ob + (colr - XD_)] =
                                               softplus_(a + brc) + 1e-4f;
                }
        }

        if (i < NPHASE - 1)
            waitall(slots, (unsigned)(i + 1), tid);
    }
}

// ---------------------------------------------------------------------------
extern "C" void kernel_launch(void* const* d_in, const int* in_sizes, int n_in,
                              void* d_out, int out_size, void* d_ws, size_t ws_size,
                              hipStream_t stream)
{
    (void)in_sizes; (void)n_in; (void)out_size; (void)ws_size;
    float* out = (float*)d_out;

    char* p = (char*)d_ws;
    auto alloc = [&](size_t bytes) { void* r = p; p += (bytes + 255) & ~(size_t)255; return r; };
    const size_t HSb = (size_t)1024 * 512 * sizeof(ushort);
    ushort* hqbf = (ushort*)alloc(2 * HSb);
    ushort* hpbf = (ushort*)alloc(2 * HSb);
    ushort* zbf  = (ushort*)alloc(2 * (size_t)1024 * 32 * sizeof(ushort));
    ushort* Wqg  = (ushort*)alloc((size_t)8 * 32 * 544 * sizeof(ushort));
    ushort* Wpg  = (ushort*)alloc((size_t)8 * 128 * 512 * sizeof(ushort));
    unsigned* bar = (unsigned*)alloc((size_t)8 * 2048 * sizeof(unsigned));

    hipMemsetAsync(bar, 0, (size_t)8 * 2048 * sizeof(unsigned), stream);

    OmniArgs a;
    a.x     = (const float*)d_in[0];
    a.eps   = (const float*)d_in[1];
    a.Wih_q = (const float*)d_in[2];
    a.Whh_q = (const float*)d_in[3];
    a.bih_q = (const float*)d_in[4];
    a.bhh_q = (const float*)d_in[5];
    a.Wqm   = (const float*)d_in[6];
    a.bqm   = (const float*)d_in[7];
    a.Wqs   = (const float*)d_in[8];
    a.bqs   = (const float*)d_in[9];
    a.Wih_p = (const float*)d_in[10];
    a.Whh_p = (const float*)d_in[11];
    a.bih_p = (const float*)d_in[12];
    a.bhh_p = (const float*)d_in[13];
    a.Wpm   = (const float*)d_in[14];
    a.bpm   = (const float*)d_in[15];
    a.Wps   = (const float*)d_in[16];
    a.bps   = (const float*)d_in[17];
    a.fu    = (const float*)d_in[18];
    a.fw    = (const float*)d_in[19];
    a.fb    = (const float*)d_in[20];
    a.hqbf = hqbf; a.hpbf = hpbf; a.zbf = zbf; a.Wqg = Wqg; a.Wpg = Wpg; a.bar = bar;
    a.o_rm = out;
    a.o_rs = out + 3891200;
    a.o_z  = out + 7782400;
    a.o_zm = out + 9420800;
    a.o_zs = out + 11059200;
    a.o_ld = out + 12697600;

    void* kargs[] = { &a };
    hipError_t err = hipLaunchCooperativeKernel((void*)omni_persist, dim3(256), dim3(512),
                                                kargs, 0, stream);
    if (err != hipSuccess) {
        // fallback: plain launch — 256 blocks, 1 block/CU, all co-resident.
        (void)hipGetLastError();
        hipLaunchKernelGGL(omni_persist, dim3(256), dim3(512), 0, stream, a);
    }
}